// Round 1
// baseline (775.753 us; speedup 1.0000x reference)
//
#include <hip/hip_runtime.h>
#include <math.h>

#define NN 50000
#define EE 800000
#define ET (EE + NN)                 // 850000 edges incl self-loops
#define NCHK ((NN + 255) / 256)      // 196 scan chunks
#define NEG 0.2f

__device__ __forceinline__ float lrelu(float x) { return x > 0.f ? x : NEG * x; }

// ---------------- CSR build (counting sort by dst) ----------------

__global__ __launch_bounds__(256) void k_init_cnt(int* cnt) {
    int i = blockIdx.x * 256 + threadIdx.x;
    if (i < NN) cnt[i] = 1;  // self-loop
}

__global__ __launch_bounds__(256) void k_hist(const int* __restrict__ eidx, int* __restrict__ cnt) {
    int i = blockIdx.x * 256 + threadIdx.x;
    if (i < EE) atomicAdd(&cnt[eidx[EE + i]], 1);
}

__global__ __launch_bounds__(256) void k_csum(const int* __restrict__ cnt, int* __restrict__ csums) {
    __shared__ int sh[256];
    int t = threadIdx.x, i = blockIdx.x * 256 + t;
    sh[t] = (i < NN) ? cnt[i] : 0;
    __syncthreads();
    for (int off = 128; off > 0; off >>= 1) {
        if (t < off) sh[t] += sh[t + off];
        __syncthreads();
    }
    if (t == 0) csums[blockIdx.x] = sh[0];
}

__global__ __launch_bounds__(256) void k_cscan(int* __restrict__ csums, int* __restrict__ rowptr) {
    __shared__ int sh[256];
    int t = threadIdx.x;
    sh[t] = (t < NCHK) ? csums[t] : 0;
    __syncthreads();
    for (int off = 1; off < 256; off <<= 1) {
        int x = (t >= off) ? sh[t - off] : 0;
        __syncthreads();
        sh[t] += x;
        __syncthreads();
    }
    int ex = (t == 0) ? 0 : sh[t - 1];
    if (t < NCHK) csums[t] = ex;
    if (t == 0) rowptr[NN] = ET;
}

__global__ __launch_bounds__(256) void k_chscan(const int* __restrict__ cnt, const int* __restrict__ csums,
                                                int* __restrict__ rowptr, int* __restrict__ cursor) {
    __shared__ int sh[256];
    int t = threadIdx.x, b = blockIdx.x, i = b * 256 + t;
    int v = (i < NN) ? cnt[i] : 0;
    sh[t] = v;
    __syncthreads();
    for (int off = 1; off < 256; off <<= 1) {
        int x = (t >= off) ? sh[t - off] : 0;
        __syncthreads();
        sh[t] += x;
        __syncthreads();
    }
    int ex = (t == 0 ? 0 : sh[t - 1]) + csums[b];
    if (i < NN) { rowptr[i] = ex; cursor[i] = ex; }
}

__global__ __launch_bounds__(256) void k_scatter(const int* __restrict__ eidx,
                                                 int* __restrict__ cursor, int* __restrict__ ssrc) {
    int i = blockIdx.x * 256 + threadIdx.x;
    if (i >= ET) return;
    int s, d;
    if (i < EE) { s = eidx[i]; d = eidx[EE + i]; } else { s = d = i - EE; }
    int pos = atomicAdd(&cursor[d], 1);
    ssrc[pos] = s;
}

// ---------------- f32 GEMM: Y[N,NOUT] = X[N,128] @ W[128,NOUT] ----------------
// block = 256 threads; tile 128 rows x 32 cols; thread = 4x4 micro-tile

template <int NOUT>
__global__ __launch_bounds__(256) void k_gemm(const float* __restrict__ X, const float* __restrict__ Wm,
                                              float* __restrict__ Y) {
    __shared__ float xs[32][129];  // [k][row]
    __shared__ float wsh[32][33];  // [k][col]
    int tid = threadIdx.x;
    int rb = blockIdx.x * 128;
    int cb = blockIdx.y * 32;
    int rg = tid >> 3;   // 0..31 -> rows rg*4..+3
    int cg = tid & 7;    // 0..7  -> cols cg*4..+3
    float acc[4][4] = {};
    for (int kc = 0; kc < 128; kc += 32) {
        int kk = (tid & 7) * 4;
        int rr = tid >> 3;  // 0..31
        #pragma unroll
        for (int p = 0; p < 4; ++p) {
            int r = rb + p * 32 + rr;
            int rs = r < NN ? r : NN - 1;
            float4 v = *reinterpret_cast<const float4*>(&X[(size_t)rs * 128 + kc + kk]);
            xs[kk + 0][p * 32 + rr] = v.x;
            xs[kk + 1][p * 32 + rr] = v.y;
            xs[kk + 2][p * 32 + rr] = v.z;
            xs[kk + 3][p * 32 + rr] = v.w;
        }
        {
            int k = tid >> 3;
            int c = (tid & 7) * 4;
            float4 wv = *reinterpret_cast<const float4*>(&Wm[(size_t)(kc + k) * NOUT + cb + c]);
            wsh[k][c] = wv.x; wsh[k][c + 1] = wv.y; wsh[k][c + 2] = wv.z; wsh[k][c + 3] = wv.w;
        }
        __syncthreads();
        #pragma unroll
        for (int k = 0; k < 32; ++k) {
            float a0 = xs[k][rg * 4 + 0], a1 = xs[k][rg * 4 + 1];
            float a2 = xs[k][rg * 4 + 2], a3 = xs[k][rg * 4 + 3];
            float b0 = wsh[k][cg * 4 + 0], b1 = wsh[k][cg * 4 + 1];
            float b2 = wsh[k][cg * 4 + 2], b3 = wsh[k][cg * 4 + 3];
            acc[0][0] += a0 * b0; acc[0][1] += a0 * b1; acc[0][2] += a0 * b2; acc[0][3] += a0 * b3;
            acc[1][0] += a1 * b0; acc[1][1] += a1 * b1; acc[1][2] += a1 * b2; acc[1][3] += a1 * b3;
            acc[2][0] += a2 * b0; acc[2][1] += a2 * b1; acc[2][2] += a2 * b2; acc[2][3] += a2 * b3;
            acc[3][0] += a3 * b0; acc[3][1] += a3 * b1; acc[3][2] += a3 * b2; acc[3][3] += a3 * b3;
        }
        __syncthreads();
    }
    #pragma unroll
    for (int i = 0; i < 4; ++i) {
        int r = rb + rg * 4 + i;
        if (r < NN) {
            #pragma unroll
            for (int j = 0; j < 4; ++j)
                Y[(size_t)r * NOUT + cb + cg * 4 + j] = acc[i][j];
        }
    }
}

// ---------------- per-node attention scalars: es/ed [N,H] ----------------

template <int CH>
__global__ __launch_bounds__(256) void k_attn_scal(const float* __restrict__ Hf,
                                                   const float* __restrict__ asrc,
                                                   const float* __restrict__ adst,
                                                   float* __restrict__ es, float* __restrict__ ed) {
    int i = blockIdx.x * 256 + threadIdx.x;  // n*4 + h
    if (i >= NN * 4) return;
    int h = i & 3, n = i >> 2;
    const float* row = Hf + (size_t)n * (4 * CH) + h * CH;
    float s = 0.f, d = 0.f;
    for (int c = 0; c < CH; ++c) {
        float v = row[c];
        s += v * asrc[h * CH + c];
        d += v * adst[h * CH + c];
    }
    es[i] = s;
    ed[i] = d;
}

// ---------------- wave-per-node online-softmax aggregation ----------------
// layers 1-3: FEAT=128, CH=32; lane handles 2 channels (one head each)

__global__ __launch_bounds__(256) void k_agg128(const float* __restrict__ Hf,
                                                const float* __restrict__ es, const float* __restrict__ ed,
                                                const int* __restrict__ rowptr, const int* __restrict__ ssrc,
                                                const float* __restrict__ bias, float* __restrict__ Yout) {
    int wid = (blockIdx.x * 256 + threadIdx.x) >> 6;
    int lane = threadIdx.x & 63;
    if (wid >= NN) return;
    int n = wid;
    int c = lane * 2;
    int h = c >> 5;  // head of both channels
    float edv = ed[n * 4 + h];
    int beg = rowptr[n], end = rowptr[n + 1];
    float m = -INFINITY, dsum = 0.f;
    float ax = 0.f, ay = 0.f;
    for (int idx = beg; idx < end; ++idx) {
        int s = ssrc[idx];
        float e = lrelu(es[s * 4 + h] + edv);
        float2 hv = *reinterpret_cast<const float2*>(&Hf[(size_t)s * 128 + c]);
        if (e > m) {
            float sc = expf(m - e);  // first iter: expf(-inf)=0
            dsum *= sc; ax *= sc; ay *= sc;
            m = e;
        }
        float p = expf(e - m);
        dsum += p;
        ax += p * hv.x;
        ay += p * hv.y;
    }
    float inv = 1.f / dsum;
    float ox = fmaxf(ax * inv + bias[c], 0.f);
    float oy = fmaxf(ay * inv + bias[c + 1], 0.f);
    Yout[(size_t)n * 128 + c] = ox;
    Yout[(size_t)n * 128 + c + 1] = oy;
}

// layer 4: FEAT=160 (H=4 x CLS=40); lane handles channels {l, l+64, l+128(if l<32)}

__global__ __launch_bounds__(256) void k_agg160(const float* __restrict__ Hf,
                                                const float* __restrict__ es, const float* __restrict__ ed,
                                                const int* __restrict__ rowptr, const int* __restrict__ ssrc,
                                                float* __restrict__ Tout) {
    int wid = (blockIdx.x * 256 + threadIdx.x) >> 6;
    int lane = threadIdx.x & 63;
    if (wid >= NN) return;
    int n = wid;
    int c0 = lane, c1 = lane + 64, c2 = lane + 128;
    int h0 = c0 / 40, h1 = c1 / 40, h2 = c2 / 40;
    bool has2 = (lane < 32);
    float ed0 = ed[n * 4 + h0];
    float ed1 = ed[n * 4 + h1];
    float ed2 = has2 ? ed[n * 4 + h2] : 0.f;
    float m0 = -INFINITY, m1 = -INFINITY, m2 = -INFINITY;
    float d0 = 0.f, d1 = 0.f, d2 = 0.f;
    float a0 = 0.f, a1 = 0.f, a2 = 0.f;
    int beg = rowptr[n], end = rowptr[n + 1];
    for (int idx = beg; idx < end; ++idx) {
        int s = ssrc[idx];
        const float* hr = Hf + (size_t)s * 160;
        float e0 = lrelu(es[s * 4 + h0] + ed0);
        float e1 = lrelu(es[s * 4 + h1] + ed1);
        if (e0 > m0) { float sc = expf(m0 - e0); d0 *= sc; a0 *= sc; m0 = e0; }
        float p0 = expf(e0 - m0); d0 += p0; a0 += p0 * hr[c0];
        if (e1 > m1) { float sc = expf(m1 - e1); d1 *= sc; a1 *= sc; m1 = e1; }
        float p1 = expf(e1 - m1); d1 += p1; a1 += p1 * hr[c1];
        if (has2) {
            float e2 = lrelu(es[s * 4 + h2] + ed2);
            if (e2 > m2) { float sc = expf(m2 - e2); d2 *= sc; a2 *= sc; m2 = e2; }
            float p2 = expf(e2 - m2); d2 += p2; a2 += p2 * hr[c2];
        }
    }
    Tout[(size_t)n * 160 + c0] = a0 / d0;
    Tout[(size_t)n * 160 + c1] = a1 / d1;
    if (has2) Tout[(size_t)n * 160 + c2] = a2 / d2;
}

__global__ __launch_bounds__(256) void k_mean(const float* __restrict__ T, const float* __restrict__ b4,
                                              float* __restrict__ out) {
    int i = blockIdx.x * 256 + threadIdx.x;
    if (i >= NN * 40) return;
    int n = i / 40;
    int cls = i - n * 40;
    const float* r = T + (size_t)n * 160 + cls;
    out[i] = 0.25f * (r[0] + r[40] + r[80] + r[120]) + b4[cls];
}

// ---------------- host launcher ----------------

extern "C" void kernel_launch(void* const* d_in, const int* in_sizes, int n_in,
                              void* d_out, int out_size, void* d_ws, size_t ws_size,
                              hipStream_t stream) {
    const float* x    = (const float*)d_in[0];
    const int*   eidx = (const int*)d_in[1];
    const float* W[4]    = {(const float*)d_in[2], (const float*)d_in[6], (const float*)d_in[10], (const float*)d_in[14]};
    const float* asrc[4] = {(const float*)d_in[3], (const float*)d_in[7], (const float*)d_in[11], (const float*)d_in[15]};
    const float* adst[4] = {(const float*)d_in[4], (const float*)d_in[8], (const float*)d_in[12], (const float*)d_in[16]};
    const float* bias[4] = {(const float*)d_in[5], (const float*)d_in[9], (const float*)d_in[13], (const float*)d_in[17]};
    float* out = (float*)d_out;

    // workspace layout
    float* hA = (float*)d_ws;                 // N*160
    float* hB = hA + (size_t)NN * 160;        // N*160
    float* es = hB + (size_t)NN * 160;        // N*4
    float* ed = es + (size_t)NN * 4;          // N*4
    int* rowptr = (int*)(ed + (size_t)NN * 4);  // N+1
    int* cnt    = rowptr + (NN + 1);            // N
    int* cursor = cnt + NN;                     // N
    int* ssrc   = cursor + NN;                  // ET
    int* csums  = ssrc + ET;                    // NCHK (<256)

    // ---- CSR build (once; reused by all 4 layers) ----
    k_init_cnt<<<(NN + 255) / 256, 256, 0, stream>>>(cnt);
    k_hist<<<(EE + 255) / 256, 256, 0, stream>>>(eidx, cnt);
    k_csum<<<NCHK, 256, 0, stream>>>(cnt, csums);
    k_cscan<<<1, 256, 0, stream>>>(csums, rowptr);
    k_chscan<<<NCHK, 256, 0, stream>>>(cnt, csums, rowptr, cursor);
    k_scatter<<<(ET + 255) / 256, 256, 0, stream>>>(eidx, cursor, ssrc);

    dim3 g128((NN + 127) / 128, 4);
    dim3 g160((NN + 127) / 128, 5);
    int aggBlocks = (NN * 64 + 255) / 256;

    // ---- layer 1: x -> hA -> agg -> hB ----
    k_gemm<128><<<g128, 256, 0, stream>>>(x, W[0], hA);
    k_attn_scal<32><<<(NN * 4 + 255) / 256, 256, 0, stream>>>(hA, asrc[0], adst[0], es, ed);
    k_agg128<<<aggBlocks, 256, 0, stream>>>(hA, es, ed, rowptr, ssrc, bias[0], hB);

    // ---- layer 2: hB -> hA -> agg -> hB ----
    k_gemm<128><<<g128, 256, 0, stream>>>(hB, W[1], hA);
    k_attn_scal<32><<<(NN * 4 + 255) / 256, 256, 0, stream>>>(hA, asrc[1], adst[1], es, ed);
    k_agg128<<<aggBlocks, 256, 0, stream>>>(hA, es, ed, rowptr, ssrc, bias[1], hB);

    // ---- layer 3 ----
    k_gemm<128><<<g128, 256, 0, stream>>>(hB, W[2], hA);
    k_attn_scal<32><<<(NN * 4 + 255) / 256, 256, 0, stream>>>(hA, asrc[2], adst[2], es, ed);
    k_agg128<<<aggBlocks, 256, 0, stream>>>(hA, es, ed, rowptr, ssrc, bias[2], hB);

    // ---- layer 4: hB -> hA(160) -> agg(per-head) -> hB(160) -> mean -> out ----
    k_gemm<160><<<g160, 256, 0, stream>>>(hB, W[3], hA);
    k_attn_scal<40><<<(NN * 4 + 255) / 256, 256, 0, stream>>>(hA, asrc[3], adst[3], es, ed);
    k_agg160<<<aggBlocks, 256, 0, stream>>>(hA, es, ed, rowptr, ssrc, hB);
    k_mean<<<(NN * 40 + 255) / 256, 256, 0, stream>>>(hB, bias[3], out);
}

// Round 2
// 610.150 us; speedup vs baseline: 1.2714x; 1.2714x over previous
//
#include <hip/hip_runtime.h>
#include <math.h>

#define NN 50000
#define EE 800000
#define ET (EE + NN)                 // 850000 edges incl self-loops
#define NCHK ((NN + 255) / 256)      // 196 scan chunks
#define NEG 0.2f

__device__ __forceinline__ float lrelu(float x) { return x > 0.f ? x : NEG * x; }

// ---------------- CSR build (counting sort by dst) ----------------

__global__ __launch_bounds__(256) void k_init_cnt(int* cnt) {
    int i = blockIdx.x * 256 + threadIdx.x;
    if (i < NN) cnt[i] = 1;  // self-loop
}

__global__ __launch_bounds__(256) void k_hist(const int* __restrict__ eidx, int* __restrict__ cnt) {
    int i = blockIdx.x * 256 + threadIdx.x;
    if (i < EE) atomicAdd(&cnt[eidx[EE + i]], 1);
}

__global__ __launch_bounds__(256) void k_csum(const int* __restrict__ cnt, int* __restrict__ csums) {
    __shared__ int sh[256];
    int t = threadIdx.x, i = blockIdx.x * 256 + t;
    sh[t] = (i < NN) ? cnt[i] : 0;
    __syncthreads();
    for (int off = 128; off > 0; off >>= 1) {
        if (t < off) sh[t] += sh[t + off];
        __syncthreads();
    }
    if (t == 0) csums[blockIdx.x] = sh[0];
}

__global__ __launch_bounds__(256) void k_cscan(int* __restrict__ csums, int* __restrict__ rowptr) {
    __shared__ int sh[256];
    int t = threadIdx.x;
    sh[t] = (t < NCHK) ? csums[t] : 0;
    __syncthreads();
    for (int off = 1; off < 256; off <<= 1) {
        int x = (t >= off) ? sh[t - off] : 0;
        __syncthreads();
        sh[t] += x;
        __syncthreads();
    }
    int ex = (t == 0) ? 0 : sh[t - 1];
    if (t < NCHK) csums[t] = ex;
    if (t == 0) rowptr[NN] = ET;
}

__global__ __launch_bounds__(256) void k_chscan(const int* __restrict__ cnt, const int* __restrict__ csums,
                                                int* __restrict__ rowptr, int* __restrict__ cursor) {
    __shared__ int sh[256];
    int t = threadIdx.x, b = blockIdx.x, i = b * 256 + t;
    int v = (i < NN) ? cnt[i] : 0;
    sh[t] = v;
    __syncthreads();
    for (int off = 1; off < 256; off <<= 1) {
        int x = (t >= off) ? sh[t - off] : 0;
        __syncthreads();
        sh[t] += x;
        __syncthreads();
    }
    int ex = (t == 0 ? 0 : sh[t - 1]) + csums[b];
    if (i < NN) { rowptr[i] = ex; cursor[i] = ex; }
}

__global__ __launch_bounds__(256) void k_scatter(const int* __restrict__ eidx,
                                                 int* __restrict__ cursor, int* __restrict__ ssrc) {
    int i = blockIdx.x * 256 + threadIdx.x;
    if (i >= ET) return;
    int s, d;
    if (i < EE) { s = eidx[i]; d = eidx[EE + i]; } else { s = d = i - EE; }
    int pos = atomicAdd(&cursor[d], 1);
    ssrc[pos] = s;
}

// ---------------- f32 GEMM: Y[N,NOUT] = X[N,128] @ W[128,NOUT] ----------------

template <int NOUT>
__global__ __launch_bounds__(256) void k_gemm(const float* __restrict__ X, const float* __restrict__ Wm,
                                              float* __restrict__ Y) {
    __shared__ float xs[32][129];  // [k][row]
    __shared__ float wsh[32][33];  // [k][col]
    int tid = threadIdx.x;
    int rb = blockIdx.x * 128;
    int cb = blockIdx.y * 32;
    int rg = tid >> 3;   // 0..31 -> rows rg*4..+3
    int cg = tid & 7;    // 0..7  -> cols cg*4..+3
    float acc[4][4] = {};
    for (int kc = 0; kc < 128; kc += 32) {
        int kk = (tid & 7) * 4;
        int rr = tid >> 3;  // 0..31
        #pragma unroll
        for (int p = 0; p < 4; ++p) {
            int r = rb + p * 32 + rr;
            int rs = r < NN ? r : NN - 1;
            float4 v = *reinterpret_cast<const float4*>(&X[(size_t)rs * 128 + kc + kk]);
            xs[kk + 0][p * 32 + rr] = v.x;
            xs[kk + 1][p * 32 + rr] = v.y;
            xs[kk + 2][p * 32 + rr] = v.z;
            xs[kk + 3][p * 32 + rr] = v.w;
        }
        {
            int k = tid >> 3;
            int c = (tid & 7) * 4;
            float4 wv = *reinterpret_cast<const float4*>(&Wm[(size_t)(kc + k) * NOUT + cb + c]);
            wsh[k][c] = wv.x; wsh[k][c + 1] = wv.y; wsh[k][c + 2] = wv.z; wsh[k][c + 3] = wv.w;
        }
        __syncthreads();
        #pragma unroll
        for (int k = 0; k < 32; ++k) {
            float a0 = xs[k][rg * 4 + 0], a1 = xs[k][rg * 4 + 1];
            float a2 = xs[k][rg * 4 + 2], a3 = xs[k][rg * 4 + 3];
            float b0 = wsh[k][cg * 4 + 0], b1 = wsh[k][cg * 4 + 1];
            float b2 = wsh[k][cg * 4 + 2], b3 = wsh[k][cg * 4 + 3];
            acc[0][0] += a0 * b0; acc[0][1] += a0 * b1; acc[0][2] += a0 * b2; acc[0][3] += a0 * b3;
            acc[1][0] += a1 * b0; acc[1][1] += a1 * b1; acc[1][2] += a1 * b2; acc[1][3] += a1 * b3;
            acc[2][0] += a2 * b0; acc[2][1] += a2 * b1; acc[2][2] += a2 * b2; acc[2][3] += a2 * b3;
            acc[3][0] += a3 * b0; acc[3][1] += a3 * b1; acc[3][2] += a3 * b2; acc[3][3] += a3 * b3;
        }
        __syncthreads();
    }
    #pragma unroll
    for (int i = 0; i < 4; ++i) {
        int r = rb + rg * 4 + i;
        if (r < NN) {
            #pragma unroll
            for (int j = 0; j < 4; ++j)
                Y[(size_t)r * NOUT + cb + cg * 4 + j] = acc[i][j];
        }
    }
}

// ---------------- per-node attention scalars: es/ed [N,H] ----------------

template <int CH>
__global__ __launch_bounds__(256) void k_attn_scal(const float* __restrict__ Hf,
                                                   const float* __restrict__ asrc,
                                                   const float* __restrict__ adst,
                                                   float* __restrict__ es, float* __restrict__ ed) {
    int i = blockIdx.x * 256 + threadIdx.x;  // n*4 + h
    if (i >= NN * 4) return;
    int h = i & 3, n = i >> 2;
    const float4* row = reinterpret_cast<const float4*>(Hf + (size_t)n * (4 * CH) + h * CH);
    const float4* As  = reinterpret_cast<const float4*>(asrc + h * CH);
    const float4* Ad  = reinterpret_cast<const float4*>(adst + h * CH);
    float s = 0.f, d = 0.f;
    #pragma unroll
    for (int c = 0; c < CH / 4; ++c) {
        float4 v = row[c], a = As[c], b = Ad[c];
        s += v.x * a.x + v.y * a.y + v.z * a.z + v.w * a.w;
        d += v.x * b.x + v.y * b.y + v.z * b.z + v.w * b.w;
    }
    es[i] = s;
    ed[i] = d;
}

// ---------------- fused two-phase wave-per-node aggregation ----------------
// Phase 1: lanes = (edge_offset 0..15) x (head 0..3): online softmax (m, d) per head,
//          butterfly-merged so every lane holds the full-class (m, 1/d).
// Phase 2: lanes = channels: alpha = __expf(e - m) / d; pure FMA accumulate.

__global__ __launch_bounds__(256) void k_agg128(const float* __restrict__ Hf,
                                                const float* __restrict__ es, const float* __restrict__ ed,
                                                const int* __restrict__ rowptr, const int* __restrict__ ssrc,
                                                const float* __restrict__ bias, float* __restrict__ Yout) {
    int wid = (blockIdx.x * 256 + threadIdx.x) >> 6;
    int lane = threadIdx.x & 63;
    if (wid >= NN) return;
    int n = wid;
    int beg = rowptr[n], end = rowptr[n + 1];

    // ---- phase 1 ----
    int h1 = lane & 3;
    int eoff = lane >> 2;
    float edv = ed[n * 4 + h1];
    float m = -1e30f, dsum = 0.f;
    for (int idx = beg + eoff; idx < end; idx += 16) {
        int s = ssrc[idx];
        float e = lrelu(es[s * 4 + h1] + edv);
        if (e > m) { dsum *= __expf(m - e); m = e; }
        dsum += __expf(e - m);
    }
    #pragma unroll
    for (int off = 4; off < 64; off <<= 1) {
        float om = __shfl_xor(m, off);
        float od = __shfl_xor(dsum, off);
        float M = fmaxf(m, om);
        dsum = dsum * __expf(m - M) + od * __expf(om - M);
        m = M;
    }
    float invd = 1.f / dsum;

    // ---- phase 2 ----
    int c = lane * 2;
    int hc = lane >> 4;                    // head of this lane's channel pair
    float Mh = __shfl(m, hc);
    float Ih = __shfl(invd, hc);
    float Eh = __shfl(edv, hc);
    float ax = 0.f, ay = 0.f;
    int idx = beg;
    int n2 = beg + ((end - beg) & ~1);
    for (; idx < n2; idx += 2) {
        int s0 = ssrc[idx], s1 = ssrc[idx + 1];
        float e0 = lrelu(es[s0 * 4 + hc] + Eh);
        float e1 = lrelu(es[s1 * 4 + hc] + Eh);
        float2 v0 = *reinterpret_cast<const float2*>(&Hf[(size_t)s0 * 128 + c]);
        float2 v1 = *reinterpret_cast<const float2*>(&Hf[(size_t)s1 * 128 + c]);
        float p0 = __expf(e0 - Mh) * Ih;
        float p1 = __expf(e1 - Mh) * Ih;
        ax += p0 * v0.x + p1 * v1.x;
        ay += p0 * v0.y + p1 * v1.y;
    }
    if (idx < end) {
        int s0 = ssrc[idx];
        float e0 = lrelu(es[s0 * 4 + hc] + Eh);
        float2 v0 = *reinterpret_cast<const float2*>(&Hf[(size_t)s0 * 128 + c]);
        float p0 = __expf(e0 - Mh) * Ih;
        ax += p0 * v0.x;
        ay += p0 * v0.y;
    }
    Yout[(size_t)n * 128 + c]     = fmaxf(ax + bias[c], 0.f);
    Yout[(size_t)n * 128 + c + 1] = fmaxf(ay + bias[c + 1], 0.f);
}

// layer 4 (FEAT=160): lane owns channels {l, l+64, l+128 (l<32)}

__global__ __launch_bounds__(256) void k_agg160(const float* __restrict__ Hf,
                                                const float* __restrict__ es, const float* __restrict__ ed,
                                                const int* __restrict__ rowptr, const int* __restrict__ ssrc,
                                                float* __restrict__ Tout) {
    int wid = (blockIdx.x * 256 + threadIdx.x) >> 6;
    int lane = threadIdx.x & 63;
    if (wid >= NN) return;
    int n = wid;
    int beg = rowptr[n], end = rowptr[n + 1];

    // ---- phase 1 ----
    int h1 = lane & 3;
    int eoff = lane >> 2;
    float edv = ed[n * 4 + h1];
    float m = -1e30f, dsum = 0.f;
    for (int idx = beg + eoff; idx < end; idx += 16) {
        int s = ssrc[idx];
        float e = lrelu(es[s * 4 + h1] + edv);
        if (e > m) { dsum *= __expf(m - e); m = e; }
        dsum += __expf(e - m);
    }
    #pragma unroll
    for (int off = 4; off < 64; off <<= 1) {
        float om = __shfl_xor(m, off);
        float od = __shfl_xor(dsum, off);
        float M = fmaxf(m, om);
        dsum = dsum * __expf(m - M) + od * __expf(om - M);
        m = M;
    }
    float invd = 1.f / dsum;

    // ---- phase 2 ----
    int c0 = lane, c1 = lane + 64, c2 = lane + 128;
    int h0 = (lane >= 40) ? 1 : 0;
    int hh1 = (lane < 16) ? 1 : ((lane < 56) ? 2 : 3);
    const int h2 = 3;
    bool has2 = (lane < 32);
    float M0 = __shfl(m, h0),  I0 = __shfl(invd, h0),  E0 = __shfl(edv, h0);
    float M1 = __shfl(m, hh1), I1 = __shfl(invd, hh1), E1 = __shfl(edv, hh1);
    float M2 = __shfl(m, h2),  I2 = __shfl(invd, h2),  E2 = __shfl(edv, h2);
    float a0 = 0.f, a1 = 0.f, a2 = 0.f;
    int idx = beg;
    int n2 = beg + ((end - beg) & ~1);
    for (; idx < n2; idx += 2) {
        int s0 = ssrc[idx], s1 = ssrc[idx + 1];
        const float* r0 = Hf + (size_t)s0 * 160;
        const float* r1 = Hf + (size_t)s1 * 160;
        float ea0 = lrelu(es[s0 * 4 + h0] + E0);
        float eb0 = lrelu(es[s1 * 4 + h0] + E0);
        float ea1 = lrelu(es[s0 * 4 + hh1] + E1);
        float eb1 = lrelu(es[s1 * 4 + hh1] + E1);
        float ea2 = lrelu(es[s0 * 4 + h2] + E2);
        float eb2 = lrelu(es[s1 * 4 + h2] + E2);
        float f00 = r0[c0], f10 = r1[c0];
        float f01 = r0[c1], f11 = r1[c1];
        float f02 = has2 ? r0[c2] : 0.f, f12 = has2 ? r1[c2] : 0.f;
        a0 += __expf(ea0 - M0) * I0 * f00 + __expf(eb0 - M0) * I0 * f10;
        a1 += __expf(ea1 - M1) * I1 * f01 + __expf(eb1 - M1) * I1 * f11;
        a2 += __expf(ea2 - M2) * I2 * f02 + __expf(eb2 - M2) * I2 * f12;
    }
    if (idx < end) {
        int s0 = ssrc[idx];
        const float* r0 = Hf + (size_t)s0 * 160;
        float ea0 = lrelu(es[s0 * 4 + h0] + E0);
        float ea1 = lrelu(es[s0 * 4 + hh1] + E1);
        float ea2 = lrelu(es[s0 * 4 + h2] + E2);
        a0 += __expf(ea0 - M0) * I0 * r0[c0];
        a1 += __expf(ea1 - M1) * I1 * r0[c1];
        if (has2) a2 += __expf(ea2 - M2) * I2 * r0[c2];
    }
    Tout[(size_t)n * 160 + c0] = a0;
    Tout[(size_t)n * 160 + c1] = a1;
    if (has2) Tout[(size_t)n * 160 + c2] = a2;
}

__global__ __launch_bounds__(256) void k_mean(const float* __restrict__ T, const float* __restrict__ b4,
                                              float* __restrict__ out) {
    int i = blockIdx.x * 256 + threadIdx.x;
    if (i >= NN * 40) return;
    int n = i / 40;
    int cls = i - n * 40;
    const float* r = T + (size_t)n * 160 + cls;
    out[i] = 0.25f * (r[0] + r[40] + r[80] + r[120]) + b4[cls];
}

// ---------------- host launcher ----------------

extern "C" void kernel_launch(void* const* d_in, const int* in_sizes, int n_in,
                              void* d_out, int out_size, void* d_ws, size_t ws_size,
                              hipStream_t stream) {
    const float* x    = (const float*)d_in[0];
    const int*   eidx = (const int*)d_in[1];
    const float* W[4]    = {(const float*)d_in[2], (const float*)d_in[6], (const float*)d_in[10], (const float*)d_in[14]};
    const float* asrc[4] = {(const float*)d_in[3], (const float*)d_in[7], (const float*)d_in[11], (const float*)d_in[15]};
    const float* adst[4] = {(const float*)d_in[4], (const float*)d_in[8], (const float*)d_in[12], (const float*)d_in[16]};
    const float* bias[4] = {(const float*)d_in[5], (const float*)d_in[9], (const float*)d_in[13], (const float*)d_in[17]};
    float* out = (float*)d_out;

    // workspace layout
    float* hA = (float*)d_ws;                 // N*160
    float* hB = hA + (size_t)NN * 160;        // N*160
    float* es = hB + (size_t)NN * 160;        // N*4
    float* ed = es + (size_t)NN * 4;          // N*4
    int* rowptr = (int*)(ed + (size_t)NN * 4);  // N+1
    int* cnt    = rowptr + (NN + 1);            // N
    int* cursor = cnt + NN;                     // N
    int* ssrc   = cursor + NN;                  // ET
    int* csums  = ssrc + ET;                    // NCHK (<256)

    // ---- CSR build (once; reused by all 4 layers) ----
    k_init_cnt<<<(NN + 255) / 256, 256, 0, stream>>>(cnt);
    k_hist<<<(EE + 255) / 256, 256, 0, stream>>>(eidx, cnt);
    k_csum<<<NCHK, 256, 0, stream>>>(cnt, csums);
    k_cscan<<<1, 256, 0, stream>>>(csums, rowptr);
    k_chscan<<<NCHK, 256, 0, stream>>>(cnt, csums, rowptr, cursor);
    k_scatter<<<(ET + 255) / 256, 256, 0, stream>>>(eidx, cursor, ssrc);

    dim3 g128((NN + 127) / 128, 4);
    dim3 g160((NN + 127) / 128, 5);
    int aggBlocks = (NN * 64 + 255) / 256;

    // ---- layer 1: x -> hA -> agg -> hB ----
    k_gemm<128><<<g128, 256, 0, stream>>>(x, W[0], hA);
    k_attn_scal<32><<<(NN * 4 + 255) / 256, 256, 0, stream>>>(hA, asrc[0], adst[0], es, ed);
    k_agg128<<<aggBlocks, 256, 0, stream>>>(hA, es, ed, rowptr, ssrc, bias[0], hB);

    // ---- layer 2 ----
    k_gemm<128><<<g128, 256, 0, stream>>>(hB, W[1], hA);
    k_attn_scal<32><<<(NN * 4 + 255) / 256, 256, 0, stream>>>(hA, asrc[1], adst[1], es, ed);
    k_agg128<<<aggBlocks, 256, 0, stream>>>(hA, es, ed, rowptr, ssrc, bias[1], hB);

    // ---- layer 3 ----
    k_gemm<128><<<g128, 256, 0, stream>>>(hB, W[2], hA);
    k_attn_scal<32><<<(NN * 4 + 255) / 256, 256, 0, stream>>>(hA, asrc[2], adst[2], es, ed);
    k_agg128<<<aggBlocks, 256, 0, stream>>>(hA, es, ed, rowptr, ssrc, bias[2], hB);

    // ---- layer 4 ----
    k_gemm<160><<<g160, 256, 0, stream>>>(hB, W[3], hA);
    k_attn_scal<40><<<(NN * 4 + 255) / 256, 256, 0, stream>>>(hA, asrc[3], adst[3], es, ed);
    k_agg160<<<aggBlocks, 256, 0, stream>>>(hA, es, ed, rowptr, ssrc, hB);
    k_mean<<<(NN * 40 + 255) / 256, 256, 0, stream>>>(hB, bias[3], out);
}